// Round 1
// baseline (1012.643 us; speedup 1.0000x reference)
//
#include <hip/hip_runtime.h>

// One-hot: out[i, j, x[i,j]] = 1.0f, else 0.0f. B=8, S=1024, C=32000.
// Output = 8*1024*32000 f32 = 1.049 GB -> pure HBM-write-bound.
// One block per (i,j) row; float4 stores; value computed by compare, so a
// single pass writes both zeros and the one (no memset + scatter ordering).

#define NUM_CLASS 32000
#define BLOCK 256

__global__ __launch_bounds__(BLOCK) void onehot_kernel(const int* __restrict__ x,
                                                       float* __restrict__ out) {
    const int row = blockIdx.x;              // 0 .. B*S-1
    const int target = x[row];               // wave-uniform scalar load
    float4* __restrict__ orow = (float4*)(out + (size_t)row * NUM_CLASS);

    const int nvec = NUM_CLASS / 4;          // 8000 float4 per row
    for (int k = threadIdx.x; k < nvec; k += BLOCK) {
        const int c = k * 4;
        float4 v;
        v.x = (c + 0 == target) ? 1.0f : 0.0f;
        v.y = (c + 1 == target) ? 1.0f : 0.0f;
        v.z = (c + 2 == target) ? 1.0f : 0.0f;
        v.w = (c + 3 == target) ? 1.0f : 0.0f;
        orow[k] = v;
    }
}

extern "C" void kernel_launch(void* const* d_in, const int* in_sizes, int n_in,
                              void* d_out, int out_size, void* d_ws, size_t ws_size,
                              hipStream_t stream) {
    const int* x = (const int*)d_in[0];
    float* out = (float*)d_out;
    const int rows = in_sizes[0];            // 8*1024 = 8192
    onehot_kernel<<<rows, BLOCK, 0, stream>>>(x, out);
}

// Round 2
// 982.016 us; speedup vs baseline: 1.0312x; 1.0312x over previous
//
#include <hip/hip_runtime.h>

// One-hot: out[i, j, x[i,j]] = 1.0f, else 0.0f. B=8, S=1024, C=32000.
// Output = 8*1024*32000 f32 = 1.049 GB -> pure HBM-write-bound (floor ~166us
// at 6.3 TB/s achievable).
//
// Strategy: two kernels.
//  1) zero_fill: pure grid-stride float4 fill of the whole output — the exact
//     access pattern of __amd_rocclr_fillBufferAligned, which measures
//     6.2-6.3 TB/s on this chip. No compares, no per-row structure.
//  2) scatter_ones: 8192 threads, each writes one 1.0f at row*C + x[row].
//     ~4us, fully coalesced read of x, scattered dword stores absorbed by L2.

#define NUM_CLASS 32000
#define BLOCK 256

__global__ __launch_bounds__(BLOCK) void zero_fill_kernel(float4* __restrict__ out,
                                                          int nvec) {
    const int stride = gridDim.x * BLOCK;
    const float4 z = make_float4(0.f, 0.f, 0.f, 0.f);
    for (int k = blockIdx.x * BLOCK + threadIdx.x; k < nvec; k += stride) {
        out[k] = z;
    }
}

__global__ __launch_bounds__(BLOCK) void scatter_ones_kernel(const int* __restrict__ x,
                                                             float* __restrict__ out,
                                                             int rows) {
    const int row = blockIdx.x * BLOCK + threadIdx.x;
    if (row < rows) {
        const int t = x[row];
        out[(size_t)row * NUM_CLASS + t] = 1.0f;
    }
}

extern "C" void kernel_launch(void* const* d_in, const int* in_sizes, int n_in,
                              void* d_out, int out_size, void* d_ws, size_t ws_size,
                              hipStream_t stream) {
    const int* x = (const int*)d_in[0];
    float* out = (float*)d_out;
    const int rows = in_sizes[0];            // 8*1024 = 8192
    const int nvec = out_size / 4;           // 65,536,000 float4

    // 8192 blocks x 256 threads = 32 blocks/CU; ~31 float4 stores per thread.
    zero_fill_kernel<<<8192, BLOCK, 0, stream>>>((float4*)out, nvec);
    scatter_ones_kernel<<<(rows + BLOCK - 1) / BLOCK, BLOCK, 0, stream>>>(x, out, rows);
}